// Round 1
// baseline (201.341 us; speedup 1.0000x reference)
//
#include <hip/hip_runtime.h>

#define DEVI __device__ __forceinline__
typedef unsigned short u16;
typedef unsigned int u32;
typedef __attribute__((ext_vector_type(4))) float f4v;
typedef __attribute__((ext_vector_type(8))) short bf8v;   // 8 bf16 for MFMA A/B
typedef __attribute__((ext_vector_type(4))) u32  u32x4;
typedef __attribute__((ext_vector_type(2))) u32  u32x2;
typedef __attribute__((ext_vector_type(4))) u16  u16x4;

#define AS1 __attribute__((address_space(1)))
#define AS3 __attribute__((address_space(3)))

DEVI u16 f2bf(float x){ union{float f;u32 u;} c{x}; u32 r=(c.u+0x7FFFu+((c.u>>16)&1u))>>16; return (u16)r; }
DEVI float bf2f(u16 b){ union{u32 u;float f;} c{(u32)b<<16}; return c.f; }
DEVI f4v mfma32(bf8v a, bf8v b, f4v c){ return __builtin_amdgcn_mfma_f32_16x16x32_bf16(a,b,c,0,0,0); }
DEVI unsigned lds_off(const void* p){ return (unsigned)(unsigned long)(AS3 const void*)p; }
DEVI void glds16(const void* g, void* l){
  __builtin_amdgcn_global_load_lds((AS1 void*)g, (AS3 void*)l, 16, 0, 0);
}

static constexpr int NH = 12, HW = 4096, D = 64, C = 768;

// ---------------- kernel 1: fp32 -> bf16 convert (x) ----------------
__global__ void qa_convx(const float* __restrict__ x, u16* __restrict__ xb, int n4){
  int i = blockIdx.x*256 + threadIdx.x;
  if(i >= n4) return;
  f4v v = ((const f4v*)x)[i];
  u16x4 o; for(int j=0;j<4;j++) o[j] = f2bf(v[j]);
  ((u16x4*)xb)[i] = o;
}

// -------------- kernel 2: fp32 [R][Cc] -> bf16 [Cc][R] transpose --------------
__global__ void qa_transp(const float* __restrict__ in, u16* __restrict__ out, int R, int Cc){
  __shared__ float tl[32][33];
  int t = threadIdx.x;
  int r0 = blockIdx.y*32, c0 = blockIdx.x*32;
  int tr = t>>3, tc = (t&7)*4;
  f4v v = *(const f4v*)&in[(r0+tr)*Cc + c0 + tc];
  for(int j=0;j<4;j++) tl[tr][tc+j] = v[j];
  __syncthreads();
  int oc = t>>3, orr = (t&7)*4;
  u16x4 o; for(int j=0;j<4;j++) o[j] = f2bf(tl[orr+j][oc]);
  *(u16x4*)&out[(c0+oc)*R + r0 + orr] = o;
}

// -------------- kernel 3: QKV GEMM  (4096 x 2304 x 768), m97-style --------------
// A = x_bf [4096][768], Bt = wqkv_t [2304][768]. K scaled by 0.125 on store.
__global__ __launch_bounds__(256,2) void qa_gemm_qkv(
    const u16* __restrict__ A, const u16* __restrict__ Bt, const float* __restrict__ bias,
    u16* __restrict__ qb, u16* __restrict__ kb, u16* __restrict__ vb){
  __shared__ u16 Al[128*32], Bl[128*32];
  const int t = threadIdx.x, lane = t&63, w = t>>6, c16 = lane&15, h4 = lane>>4;
  const int m0 = blockIdx.y*128, n0 = blockIdx.x*128;
  const int wr = w>>1, wc = w&1;
  f4v acc[4][4] = {};
  for(int k0 = 0; k0 < 768; k0 += 32){
    __syncthreads();
    for(int i=0;i<2;i++){
      int off = i*4096 + w*1024 + lane*16;        // byte offset within 8KB tile
      int row = off>>6, kk = (off&63)>>1;
      glds16(A  + (size_t)(m0+row)*768 + k0 + kk, (u16*)Al + i*2048 + w*512);
      glds16(Bt + (size_t)(n0+row)*768 + k0 + kk, (u16*)Bl + i*2048 + w*512);
    }
    __syncthreads();
    bf8v a[4], b[4];
    for(int mt=0;mt<4;mt++) a[mt] = *(const bf8v*)&Al[(wr*64+mt*16+c16)*32 + h4*8];
    for(int nt=0;nt<4;nt++) b[nt] = *(const bf8v*)&Bl[(wc*64+nt*16+c16)*32 + h4*8];
    for(int mt=0;mt<4;mt++) for(int nt=0;nt<4;nt++) acc[mt][nt] = mfma32(a[mt], b[nt], acc[mt][nt]);
  }
  for(int nt=0;nt<4;nt++){
    int col = n0 + wc*64 + nt*16 + c16;
    float bv = bias[col];
    int which = col/768, head = (col>>6)%12, d = col&63;
    u16* dst = which==0 ? qb : (which==1 ? kb : vb);
    float sc = (which==1) ? 0.125f : 1.0f;
    for(int mt=0;mt<4;mt++) for(int r=0;r<4;r++){
      int row = m0 + wr*64 + mt*16 + 4*h4 + r;
      dst[((size_t)(head<<12)+row)*64 + d] = f2bf((acc[mt][nt][r] + bv)*sc);
    }
  }
}

// -------------- kernel 4: rel-pos bias tables via MFMA --------------
// RH[head][qh][qw][kh] = sum_d q*relh[qh-kh+63],  RW[...][kw] = sum_d q*relw[qw-kw+63]
__global__ __launch_bounds__(256) void qa_rel(
    const u16* __restrict__ qbuf, const float* __restrict__ rph, const float* __restrict__ rpw,
    u16* __restrict__ RH, u16* __restrict__ RW){
  const int t = threadIdx.x, lane = t&63, w = t>>6, c16 = lane&15, h4 = lane>>4;
  const int qh = blockIdx.x, head = blockIdx.y;
  __shared__ u16 ql[64*72], hl[64*72], wl[128*72];
  { // stage q (bf16) and tables (fp32->bf16)
    int row = t>>2, d0 = (t&3)*16;
    const u16* src = qbuf + ((size_t)(head<<12)+(qh<<6)+row)*64 + d0;
    *(u32x4*)&ql[row*72+d0]   = *(const u32x4*)src;
    *(u32x4*)&ql[row*72+d0+8] = *(const u32x4*)(src+8);
    for(int j=0;j<16;j++) hl[row*72+d0+j] = f2bf(rph[(qh+row)*64 + d0 + j]);
    int rw_r = t>>1, rd0 = (t&1)*32;
    for(int j=0;j<32;j++) wl[rw_r*72+rd0+j] = (rw_r<127) ? f2bf(rpw[rw_r*64+rd0+j]) : (u16)0;
  }
  __syncthreads();
  if(w < 2){ // G'[qw][c] = q @ hl^T ; kh = 63 - c
    bf8v a[2][2]; f4v acc[2][4] = {};
    for(int mt=0;mt<2;mt++) for(int ch=0;ch<2;ch++)
      a[mt][ch] = *(const bf8v*)&ql[(w*32+mt*16+c16)*72 + ch*32 + h4*8];
    for(int nt=0;nt<4;nt++) for(int ch=0;ch<2;ch++){
      bf8v b = *(const bf8v*)&hl[(nt*16+c16)*72 + ch*32 + h4*8];
      for(int mt=0;mt<2;mt++) acc[mt][nt] = mfma32(a[mt][ch], b, acc[mt][nt]);
    }
    for(int mt=0;mt<2;mt++) for(int nt=0;nt<4;nt++) for(int r=0;r<4;r++){
      int qw = w*32+mt*16+4*h4+r, c = nt*16+c16, kh = 63 - c;
      RH[((size_t)(head*64+qh)*64+qw)*64 + kh] = f2bf(acc[mt][nt][r]);
    }
  } else { // G[qw][c] = q @ wl^T (128 cols); kw = qw + 63 - c
    bf8v a[2][2]; f4v acc[2][8] = {};
    for(int mt=0;mt<2;mt++) for(int ch=0;ch<2;ch++)
      a[mt][ch] = *(const bf8v*)&ql[((w-2)*32+mt*16+c16)*72 + ch*32 + h4*8];
    for(int nt=0;nt<8;nt++) for(int ch=0;ch<2;ch++){
      bf8v b = *(const bf8v*)&wl[(nt*16+c16)*72 + ch*32 + h4*8];
      for(int mt=0;mt<2;mt++) acc[mt][nt] = mfma32(a[mt][ch], b, acc[mt][nt]);
    }
    for(int mt=0;mt<2;mt++) for(int nt=0;nt<8;nt++) for(int r=0;r<4;r++){
      int qw = (w-2)*32+mt*16+4*h4+r, c = nt*16+c16, kw = qw + 63 - c;
      if((unsigned)kw < 64u) RW[((size_t)(head*64+qh)*64+qw)*64 + kw] = f2bf(acc[mt][nt][r]);
    }
  }
}

// -------------- kernel 5: fused flash attention --------------
// block = (qh, head): 64 q-rows, loop 64-key tiles. No max-subtraction (logits bounded ~|6|).
__global__ __launch_bounds__(256,2) void qa_attn(
    const u16* __restrict__ qb, const u16* __restrict__ kb, const u16* __restrict__ vb,
    const u16* __restrict__ RH, const u16* __restrict__ RW, u16* __restrict__ ob){
  const int t = threadIdx.x, lane = t&63, w = t>>6, c16 = lane&15, h4 = lane>>4;
  const int qh = blockIdx.x, head = blockIdx.y;
  __shared__ u16 Kl[64*64];        // [key][d], XOR-swizzled ^((key&7)<<4) on byte addr
  __shared__ u16 Vl[64*64];        // block-permuted subtiled for ds_read_b64_tr_b16
  __shared__ u16 Pl[4][16*72];     // per-wave P tile, stride 72
  __shared__ u16 RHl[64*68], RWl[64*68];
  { // stage RH/RW tiles for this (head,qh): stride 68 => conflict-free reads
    int row = t>>2, k0 = (t&3)*16;
    const u16* sh = RH + ((size_t)(head*64+qh)*64+row)*64 + k0;
    const u16* sw = RW + ((size_t)(head*64+qh)*64+row)*64 + k0;
    for(int j=0;j<4;j++){
      *(u32x2*)&RHl[row*68+k0+j*4] = *(const u32x2*)(sh+j*4);
      *(u32x2*)&RWl[row*68+k0+j*4] = *(const u32x2*)(sw+j*4);
    }
  }
  const int qrow = (qh<<6) + w*16 + c16;
  bf8v qa0 = *(const bf8v*)&qb[((size_t)(head<<12)+qrow)*64 + h4*8];
  bf8v qa1 = *(const bf8v*)&qb[((size_t)(head<<12)+qrow)*64 + 32 + h4*8];
  f4v oacc[4] = {}; float ps[4] = {0.f,0.f,0.f,0.f};
  const int wq0 = w*16;
  const unsigned vbase = lds_off(Vl) + lane*8;
  u16* Pw = Pl[w];

  for(int kt=0;kt<64;kt++){
    __syncthreads();
    for(int cc=0;cc<2;cc++){ // stage K (swizzled) + V (permuted subtiled)
      int idx = cc*256 + t, row = idx>>3, d0 = (idx&7)*8;
      const size_t gsrc = ((size_t)(head<<12)+(kt<<6)+row)*64 + d0;
      u32x4 kv = *(const u32x4*)&kb[gsrc];
      *(u32x4*)((char*)Kl + ((row*128 + d0*2) ^ ((row&7)<<4))) = kv;
      u32x4 vv = *(const u32x4*)&vb[gsrc];
      int slot = (row&32) | ((row&4)<<2) | ((row&24)>>1) | (row&3);
      *(u32x4*)((char*)Vl + ((d0>>4)*2048 + slot*32 + (d0&15)*2)) = vv;
    }
    __syncthreads();
    float rh_r[4];
    for(int r=0;r<4;r++) rh_r[r] = bf2f(RHl[(wq0+4*h4+r)*68 + kt]);
    f4v p[4];
    for(int nt=0;nt<4;nt++){
      f4v s;
      for(int r=0;r<4;r++) s[r] = rh_r[r] + bf2f(RWl[(wq0+4*h4+r)*68 + nt*16 + c16]);
      int kr = nt*16 + c16;
      bf8v b0 = *(const bf8v*)((char*)Kl + ((kr*128      + h4*16) ^ ((kr&7)<<4)));
      bf8v b1 = *(const bf8v*)((char*)Kl + ((kr*128 + 64 + h4*16) ^ ((kr&7)<<4)));
      s = mfma32(qa0, b0, s);
      s = mfma32(qa1, b1, s);
      for(int r=0;r<4;r++) p[nt][r] = __expf(s[r]);
    }
    for(int r=0;r<4;r++) ps[r] += p[0][r]+p[1][r]+p[2][r]+p[3][r];
    for(int nt=0;nt<4;nt++) for(int r=0;r<4;r++)
      Pw[(4*h4+r)*72 + nt*16 + c16] = f2bf(p[nt][r]);
    bf8v pa0 = *(const bf8v*)&Pw[c16*72 + h4*8];
    bf8v pa1 = *(const bf8v*)&Pw[c16*72 + 32 + h4*8];
    #pragma unroll
    for(int dt=0;dt<4;dt++){
      unsigned long t00,t01,t10,t11;
      asm volatile(
        "ds_read_b64_tr_b16 %0, %4 offset:%c5\n\t"
        "ds_read_b64_tr_b16 %1, %4 offset:%c6\n\t"
        "ds_read_b64_tr_b16 %2, %4 offset:%c7\n\t"
        "ds_read_b64_tr_b16 %3, %4 offset:%c8\n\t"
        "s_waitcnt lgkmcnt(0)"
        : "=&v"(t00), "=&v"(t01), "=&v"(t10), "=&v"(t11)
        : "v"(vbase), "i"(dt*2048), "i"(dt*2048+512), "i"(dt*2048+1024), "i"(dt*2048+1536)
        : "memory");
      union { struct{ unsigned long a,b; } q; bf8v v; } u0, u1;
      u0.q.a = t00; u0.q.b = t01; u1.q.a = t10; u1.q.b = t11;
      oacc[dt] = mfma32(pa0, u0.v, oacc[dt]);
      oacc[dt] = mfma32(pa1, u1.v, oacc[dt]);
    }
  }
  for(int r=0;r<4;r++){
    float v = ps[r];
    v += __shfl_xor(v,1); v += __shfl_xor(v,2); v += __shfl_xor(v,4); v += __shfl_xor(v,8);
    ps[r] = 1.0f / v;
  }
  const int m = (qh<<6) + wq0 + 4*h4;
  for(int dt=0;dt<4;dt++) for(int r=0;r<4;r++)
    ob[(size_t)(m+r)*768 + (head<<6) + dt*16 + c16] = f2bf(oacc[dt][r]*ps[r]);
}

// -------------- kernel 6: output GEMM (4096 x 768 x 768) --------------
__global__ __launch_bounds__(256,2) void qa_gemm_out(
    const u16* __restrict__ A, const u16* __restrict__ Bt, const float* __restrict__ bias,
    float* __restrict__ out){
  __shared__ u16 Al[128*32], Bl[128*32];
  const int t = threadIdx.x, lane = t&63, w = t>>6, c16 = lane&15, h4 = lane>>4;
  const int m0 = blockIdx.y*128, n0 = blockIdx.x*128;
  const int wr = w>>1, wc = w&1;
  f4v acc[4][4] = {};
  for(int k0 = 0; k0 < 768; k0 += 32){
    __syncthreads();
    for(int i=0;i<2;i++){
      int off = i*4096 + w*1024 + lane*16;
      int row = off>>6, kk = (off&63)>>1;
      glds16(A  + (size_t)(m0+row)*768 + k0 + kk, (u16*)Al + i*2048 + w*512);
      glds16(Bt + (size_t)(n0+row)*768 + k0 + kk, (u16*)Bl + i*2048 + w*512);
    }
    __syncthreads();
    bf8v a[4], b[4];
    for(int mt=0;mt<4;mt++) a[mt] = *(const bf8v*)&Al[(wr*64+mt*16+c16)*32 + h4*8];
    for(int nt=0;nt<4;nt++) b[nt] = *(const bf8v*)&Bl[(wc*64+nt*16+c16)*32 + h4*8];
    for(int mt=0;mt<4;mt++) for(int nt=0;nt<4;nt++) acc[mt][nt] = mfma32(a[mt], b[nt], acc[mt][nt]);
  }
  for(int nt=0;nt<4;nt++){
    int col = n0 + wc*64 + nt*16 + c16;
    float bv = bias[col];
    for(int mt=0;mt<4;mt++) for(int r=0;r<4;r++){
      int row = m0 + wr*64 + mt*16 + 4*h4 + r;
      out[(size_t)row*768 + col] = acc[mt][nt][r] + bv;
    }
  }
}

extern "C" void kernel_launch(void* const* d_in, const int* in_sizes, int n_in,
                              void* d_out, int out_size, void* d_ws, size_t ws_size,
                              hipStream_t stream){
  const float* x    = (const float*)d_in[0];
  const float* wqkv = (const float*)d_in[1];
  const float* bqkv = (const float*)d_in[2];
  const float* wo   = (const float*)d_in[3];
  const float* bo   = (const float*)d_in[4];
  const float* rph  = (const float*)d_in[5];
  const float* rpw  = (const float*)d_in[6];
  float* out = (float*)d_out;

  size_t off = 0;
  auto alloc = [&](size_t bytes){ void* p = (char*)d_ws + off; off += (bytes + 255) & ~(size_t)255; return p; };
  u16* x_bf   = (u16*)alloc((size_t)HW*C*2);
  u16* wqkv_t = (u16*)alloc((size_t)2304*768*2);
  u16* wo_t   = (u16*)alloc((size_t)768*768*2);
  u16* q_buf  = (u16*)alloc((size_t)NH*HW*D*2);
  u16* k_buf  = (u16*)alloc((size_t)NH*HW*D*2);
  u16* v_buf  = (u16*)alloc((size_t)NH*HW*D*2);
  u16* rh_buf = (u16*)alloc((size_t)NH*64*64*64*2);
  u16* rw_buf = (u16*)alloc((size_t)NH*64*64*64*2);
  u16* o_buf  = (u16*)alloc((size_t)HW*C*2);

  int n4 = HW*C/4;
  qa_convx<<<(n4+255)/256, 256, 0, stream>>>(x, x_bf, n4);
  qa_transp<<<dim3(2304/32, 768/32), 256, 0, stream>>>(wqkv, wqkv_t, 768, 2304);
  qa_transp<<<dim3(768/32, 768/32),  256, 0, stream>>>(wo,   wo_t,   768, 768);
  qa_gemm_qkv<<<dim3(2304/128, HW/128), 256, 0, stream>>>(x_bf, wqkv_t, bqkv, q_buf, k_buf, v_buf);
  qa_rel<<<dim3(64, NH), 256, 0, stream>>>(q_buf, rph, rpw, rh_buf, rw_buf);
  qa_attn<<<dim3(64, NH), 256, 0, stream>>>(q_buf, k_buf, v_buf, rh_buf, rw_buf, o_buf);
  qa_gemm_out<<<dim3(768/128, HW/128), 256, 0, stream>>>(o_buf, wo_t, bo, out);
}

// Round 2
// 163.912 us; speedup vs baseline: 1.2283x; 1.2283x over previous
//
#include <hip/hip_runtime.h>

#define DEVI __device__ __forceinline__
typedef unsigned short u16;
typedef unsigned int u32;
typedef __attribute__((ext_vector_type(4))) float f4v;
typedef __attribute__((ext_vector_type(8))) short bf8v;   // 8 bf16 for MFMA A/B
typedef __attribute__((ext_vector_type(4))) u32  u32x4;
typedef __attribute__((ext_vector_type(2))) u32  u32x2;
typedef __attribute__((ext_vector_type(4))) u16  u16x4;

#define AS1 __attribute__((address_space(1)))
#define AS3 __attribute__((address_space(3)))

DEVI u16 f2bf(float x){ union{float f;u32 u;} c{x}; u32 r=(c.u+0x7FFFu+((c.u>>16)&1u))>>16; return (u16)r; }
DEVI float bf2f(u16 b){ union{u32 u;float f;} c{(u32)b<<16}; return c.f; }
DEVI f4v mfma32(bf8v a, bf8v b, f4v c){ return __builtin_amdgcn_mfma_f32_16x16x32_bf16(a,b,c,0,0,0); }
DEVI unsigned lds_off(const void* p){ return (unsigned)(unsigned long)(AS3 const void*)p; }
DEVI void glds16(const void* g, void* l){
  __builtin_amdgcn_global_load_lds((AS1 void*)g, (AS3 void*)l, 16, 0, 0);
}

static constexpr int NH = 12, HW = 4096, D = 64, C = 768;
static constexpr float LOG2E = 1.44269504f;

// ---------------- kernel 1: fp32 -> bf16 convert (x) ----------------
__global__ void qa_convx(const float* __restrict__ x, u16* __restrict__ xb, int n4){
  int i = blockIdx.x*256 + threadIdx.x;
  if(i >= n4) return;
  f4v v = ((const f4v*)x)[i];
  u16x4 o; for(int j=0;j<4;j++) o[j] = f2bf(v[j]);
  ((u16x4*)xb)[i] = o;
}

// -------------- kernel 2: fp32 [R][Cc] -> bf16 [Cc][R] transpose --------------
__global__ void qa_transp(const float* __restrict__ in, u16* __restrict__ out, int R, int Cc){
  __shared__ float tl[32][33];
  int t = threadIdx.x;
  int r0 = blockIdx.y*32, c0 = blockIdx.x*32;
  int tr = t>>3, tc = (t&7)*4;
  f4v v = *(const f4v*)&in[(r0+tr)*Cc + c0 + tc];
  for(int j=0;j<4;j++) tl[tr][tc+j] = v[j];
  __syncthreads();
  int oc = t>>3, orr = (t&7)*4;
  u16x4 o; for(int j=0;j<4;j++) o[j] = f2bf(tl[orr+j][oc]);
  *(u16x4*)&out[(c0+oc)*R + r0 + orr] = o;
}

// -------------- kernel 3: QKV GEMM  (4096 x 2304 x 768) --------------
// A = x_bf [4096][768], Bt = wqkv_t [2304][768]. K scaled by 0.125*log2e on store.
__global__ __launch_bounds__(256,2) void qa_gemm_qkv(
    const u16* __restrict__ A, const u16* __restrict__ Bt, const float* __restrict__ bias,
    u16* __restrict__ qb, u16* __restrict__ kb, u16* __restrict__ vb){
  __shared__ u16 Al[128*32], Bl[128*32];
  const int t = threadIdx.x, lane = t&63, w = t>>6, c16 = lane&15, h4 = lane>>4;
  const int m0 = blockIdx.y*128, n0 = blockIdx.x*128;
  const int wr = w>>1, wc = w&1;
  f4v acc[4][4] = {};
  for(int k0 = 0; k0 < 768; k0 += 32){
    __syncthreads();
    for(int i=0;i<2;i++){
      int off = i*4096 + w*1024 + lane*16;        // byte offset within 8KB tile
      int row = off>>6, kk = (off&63)>>1;
      glds16(A  + (size_t)(m0+row)*768 + k0 + kk, (u16*)Al + i*2048 + w*512);
      glds16(Bt + (size_t)(n0+row)*768 + k0 + kk, (u16*)Bl + i*2048 + w*512);
    }
    __syncthreads();
    bf8v a[4], b[4];
    for(int mt=0;mt<4;mt++) a[mt] = *(const bf8v*)&Al[(wr*64+mt*16+c16)*32 + h4*8];
    for(int nt=0;nt<4;nt++) b[nt] = *(const bf8v*)&Bl[(wc*64+nt*16+c16)*32 + h4*8];
    for(int mt=0;mt<4;mt++) for(int nt=0;nt<4;nt++) acc[mt][nt] = mfma32(a[mt], b[nt], acc[mt][nt]);
  }
  for(int nt=0;nt<4;nt++){
    int col = n0 + wc*64 + nt*16 + c16;
    float bv = bias[col];
    int which = col/768, head = (col>>6)%12, d = col&63;
    u16* dst = which==0 ? qb : (which==1 ? kb : vb);
    float sc = (which==1) ? 0.125f*LOG2E : 1.0f;
    for(int mt=0;mt<4;mt++) for(int r=0;r<4;r++){
      int row = m0 + wr*64 + mt*16 + 4*h4 + r;
      dst[((size_t)(head<<12)+row)*64 + d] = f2bf((acc[mt][nt][r] + bv)*sc);
    }
  }
}

// -------------- kernel 4: rel-pos bias tables via MFMA (scaled by log2e) --------------
// RH_t[head][qh][kh][qw] (transposed!), RW[head][qh][qw][kw]
__global__ __launch_bounds__(256) void qa_rel(
    const u16* __restrict__ qbuf, const float* __restrict__ rph, const float* __restrict__ rpw,
    u16* __restrict__ RHt, u16* __restrict__ RW){
  const int t = threadIdx.x, lane = t&63, w = t>>6, c16 = lane&15, h4 = lane>>4;
  const int qh = blockIdx.x, head = blockIdx.y;
  __shared__ u16 ql[64*72], hl[64*72], wl[128*72];
  { // stage q (bf16) and tables (fp32->bf16)
    int row = t>>2, d0 = (t&3)*16;
    const u16* src = qbuf + ((size_t)(head<<12)+(qh<<6)+row)*64 + d0;
    *(u32x4*)&ql[row*72+d0]   = *(const u32x4*)src;
    *(u32x4*)&ql[row*72+d0+8] = *(const u32x4*)(src+8);
    for(int j=0;j<16;j++) hl[row*72+d0+j] = f2bf(rph[(qh+row)*64 + d0 + j]);
    int rw_r = t>>1, rd0 = (t&1)*32;
    for(int j=0;j<32;j++) wl[rw_r*72+rd0+j] = (rw_r<127) ? f2bf(rpw[rw_r*64+rd0+j]) : (u16)0;
  }
  __syncthreads();
  if(w < 2){ // G'[qw][c] = q @ hl^T ; kh = 63 - c
    bf8v a[2][2]; f4v acc[2][4] = {};
    for(int mt=0;mt<2;mt++) for(int ch=0;ch<2;ch++)
      a[mt][ch] = *(const bf8v*)&ql[(w*32+mt*16+c16)*72 + ch*32 + h4*8];
    for(int nt=0;nt<4;nt++) for(int ch=0;ch<2;ch++){
      bf8v b = *(const bf8v*)&hl[(nt*16+c16)*72 + ch*32 + h4*8];
      for(int mt=0;mt<2;mt++) acc[mt][nt] = mfma32(a[mt][ch], b, acc[mt][nt]);
    }
    for(int mt=0;mt<2;mt++) for(int nt=0;nt<4;nt++) for(int r=0;r<4;r++){
      int qw = w*32+mt*16+4*h4+r, c = nt*16+c16, kh = 63 - c;
      RHt[((size_t)(head*64+qh)*64+kh)*64 + qw] = f2bf(acc[mt][nt][r]*LOG2E);
    }
  } else { // G[qw][c] = q @ wl^T (128 cols); kw = qw + 63 - c
    bf8v a[2][2]; f4v acc[2][8] = {};
    for(int mt=0;mt<2;mt++) for(int ch=0;ch<2;ch++)
      a[mt][ch] = *(const bf8v*)&ql[((w-2)*32+mt*16+c16)*72 + ch*32 + h4*8];
    for(int nt=0;nt<8;nt++) for(int ch=0;ch<2;ch++){
      bf8v b = *(const bf8v*)&wl[(nt*16+c16)*72 + ch*32 + h4*8];
      for(int mt=0;mt<2;mt++) acc[mt][nt] = mfma32(a[mt][ch], b, acc[mt][nt]);
    }
    for(int mt=0;mt<2;mt++) for(int nt=0;nt<8;nt++) for(int r=0;r<4;r++){
      int qw = (w-2)*32+mt*16+4*h4+r, c = nt*16+c16, kw = qw + 63 - c;
      if((unsigned)kw < 64u) RW[((size_t)(head*64+qh)*64+qw)*64 + kw] = f2bf(acc[mt][nt][r]*LOG2E);
    }
  }
}

// -------------- kernel 5: fused flash attention (rewritten) --------------
// block = 128 threads (2 waves x 32 qrows = 64 qrows), grid 768 (XCD-swizzled).
// Swapped QK^T (S^T in regs), in-register P^T frags, O^T output, glds16 dbuf pipeline.
__global__ __launch_bounds__(128,2) void qa_attn(
    const u16* __restrict__ qb, const u16* __restrict__ kb, const u16* __restrict__ vb,
    const u16* __restrict__ RHt, const u16* __restrict__ RW, u16* __restrict__ ob){
  __shared__ u16 Kl[2][4096];   // [buf][key][d], content at byte b = K[b ^ ((b>>7&7)<<4)]
  __shared__ u16 Vl[2][4096];   // [buf], subtiled: (d>>4)*2048B + key*32B + (d&15)*2B
  __shared__ u16 RHl[4096];     // [kt][qrow] for this (head, qt)
  const int t = threadIdx.x, lane = t&63, w = t>>6, c16 = lane&15, h4 = lane>>4;
  const int bid = blockIdx.x;
  const int wid = (bid&7)*96 + (bid>>3);       // XCD swizzle: <=2 heads per XCD
  const int head = wid>>6, qt = wid&63;

  // prologue: stage RH tile (linear 8KB)
  const u16* rhg = RHt + ((size_t)(head*64+qt))*4096;
  for(int i=0;i<4;i++)
    glds16(rhg + (i*128 + t)*8, (u16*)RHl + (i*128 + w*64)*8);

  // staging source offsets (16B units), fold K swizzle / V subtile permutation into source
  int koff[4], voff[4];
  for(int i=0;i<4;i++){
    int u = i*128 + t;
    koff[i] = (u ^ ((u>>3)&7))*8;                      // elements
    int key = ((u>>1)&3) | (((u>>3)&15)<<2);
    int d0  = ((u&1)<<3) | (((u>>7)&3)<<4);
    voff[i] = key*64 + d0;
  }
  const u16* kg = kb + (size_t)head*262144;
  const u16* vg = vb + (size_t)head*262144;
  const u16* kp = kg; const u16* vp = vg;
  for(int i=0;i<4;i++){                                 // tile 0 -> buf 0
    glds16(kp + koff[i], (u16*)Kl[0] + (i*128 + w*64)*8);
    glds16(vp + voff[i], (u16*)Vl[0] + (i*128 + w*64)*8);
  }
  kp += 4096; vp += 4096;

  // Q fragments (B-operand): lane holds Q[qrow = q0r+qc*16+c16][d = 8*h4+j]
  const int q0r = qt*64 + w*32;
  bf8v qa[2][2];
  for(int qc=0;qc<2;qc++){
    const u16* qsrc = qb + ((size_t)head*4096 + q0r + qc*16 + c16)*64;
    qa[qc][0] = *(const bf8v*)(qsrc + h4*8);
    qa[qc][1] = *(const bf8v*)(qsrc + 32 + h4*8);
  }
  // RW bias in registers: rw[nt][qc][r] for kw = nt*16+4*h4+r (already *log2e)
  float rw[4][2][4];
  for(int nt=0;nt<4;nt++) for(int qc=0;qc<2;qc++) for(int r=0;r<4;r++){
    int qw = (w*32 + qc*16 + c16), kw = nt*16 + 4*h4 + r;
    rw[nt][qc][r] = bf2f(RW[(((size_t)(head*64+qt))*64 + qw)*64 + kw]);
  }

  f4v oacc[4][2] = {}; float ps[2] = {0.f, 0.f};
  unsigned vcur = lds_off(Vl) + lane*8;
  const int kq0 = (h4*16) ^ ((c16&7)<<4);
  const int kq1 = (h4*16 + 64) ^ ((c16&7)<<4);
  const int kA  = c16*128;

  for(int kt=0; kt<64; kt++){
    // issue next tile into the other buffer (kt=63 wraps harmlessly to tile 0)
    if(kt == 63){ kp = kg; vp = vg; }
    {
      u16* Kn = (u16*)Kl[(kt+1)&1]; u16* Vn = (u16*)Vl[(kt+1)&1];
      for(int i=0;i<4;i++){
        glds16(kp + koff[i], Kn + (i*128 + w*64)*8);
        glds16(vp + voff[i], Vn + (i*128 + w*64)*8);
      }
    }
    kp += 4096; vp += 4096;
    asm volatile("s_waitcnt vmcnt(8)\n\ts_barrier" ::: "memory");  // tile kt ready; kt+1 in flight

    const char* Kc = (const char*)Kl + (kt&1)*8192;
    float rh0 = bf2f(RHl[kt*64 + w*32 + c16]);
    float rh1 = bf2f(RHl[kt*64 + w*32 + 16 + c16]);
    f4v p[4][2];
    #pragma unroll
    for(int nt=0;nt<4;nt++){
      bf8v k0 = *(const bf8v*)(Kc + kA + nt*2048 + kq0);
      bf8v k1 = *(const bf8v*)(Kc + kA + nt*2048 + kq1);
      #pragma unroll
      for(int qc=0;qc<2;qc++){
        f4v s;
        float rh = qc ? rh1 : rh0;
        for(int r=0;r<4;r++) s[r] = rh + rw[nt][qc][r];
        s = mfma32(k0, qa[qc][0], s);          // S^T[key=nt*16+4h4+r][qrow=c16]
        s = mfma32(k1, qa[qc][1], s);
        f4v pe;
        for(int r=0;r<4;r++) pe[r] = __builtin_amdgcn_exp2f(s[r]);
        p[nt][qc] = pe;
        ps[qc] += pe[0]+pe[1]+pe[2]+pe[3];
      }
    }
    // pack P^T fragments: pb[half][qc] elem e = p[half*2 + (e>>2)][qc][e&3]
    union U8 { u32 w[4]; bf8v v; };
    U8 pb[2][2];
    #pragma unroll
    for(int half=0;half<2;half++)
      #pragma unroll
      for(int qc=0;qc<2;qc++)
        #pragma unroll
        for(int i=0;i<4;i++){
          int nt = half*2 + (i>>1), r0 = (i&1)*2;
          asm("v_cvt_pk_bf16_f32 %0, %1, %2"
              : "=v"(pb[half][qc].w[i]) : "v"(p[nt][qc][r0]), "v"(p[nt][qc][r0+1]));
        }
    // PV: A = V^T frag via tr-reads (keys 4h4+(e&3)+16(e>>2) matches pb sigma)
    #pragma unroll
    for(int dt=0;dt<4;dt++){
      unsigned long t00,t01,t10,t11;
      asm volatile(
        "ds_read_b64_tr_b16 %0, %4 offset:%c5\n\t"
        "ds_read_b64_tr_b16 %1, %4 offset:%c6\n\t"
        "ds_read_b64_tr_b16 %2, %4 offset:%c7\n\t"
        "ds_read_b64_tr_b16 %3, %4 offset:%c8\n\t"
        "s_waitcnt lgkmcnt(0)"
        : "=&v"(t00), "=&v"(t01), "=&v"(t10), "=&v"(t11)
        : "v"(vcur), "i"(dt*2048), "i"(dt*2048+512), "i"(dt*2048+1024), "i"(dt*2048+1536)
        : "memory");
      union { struct{ unsigned long a,b; } q; bf8v v; } v01, v23;
      v01.q.a = t00; v01.q.b = t01; v23.q.a = t10; v23.q.b = t11;
      #pragma unroll
      for(int qc=0;qc<2;qc++){
        oacc[dt][qc] = mfma32(v01.v, pb[0][qc].v, oacc[dt][qc]);
        oacc[dt][qc] = mfma32(v23.v, pb[1][qc].v, oacc[dt][qc]);
      }
    }
    asm volatile("s_waitcnt lgkmcnt(0)\n\ts_barrier" ::: "memory");  // reads done before overwrite
    vcur ^= 8192;
  }
  asm volatile("s_waitcnt vmcnt(0)" ::: "memory");  // drain wrap-around DMA before exit

  #pragma unroll
  for(int qc=0;qc<2;qc++){
    float v = ps[qc];
    v += __shfl_xor(v, 16); v += __shfl_xor(v, 32);
    float inv = 1.0f / v;
    const size_t orow = (size_t)(q0r + qc*16 + c16)*768 + head*64;
    #pragma unroll
    for(int dt=0;dt<4;dt++){
      u16x4 ov;
      for(int r=0;r<4;r++) ov[r] = f2bf(oacc[dt][qc][r]*inv);
      *(u16x4*)&ob[orow + dt*16 + 4*h4] = ov;     // O^T rows d=dt*16+4h4+r, col qrow
    }
  }
}

// -------------- kernel 6: output GEMM (4096 x 768 x 768) --------------
__global__ __launch_bounds__(256,2) void qa_gemm_out(
    const u16* __restrict__ A, const u16* __restrict__ Bt, const float* __restrict__ bias,
    float* __restrict__ out){
  __shared__ u16 Al[128*32], Bl[128*32];
  const int t = threadIdx.x, lane = t&63, w = t>>6, c16 = lane&15, h4 = lane>>4;
  const int m0 = blockIdx.y*128, n0 = blockIdx.x*128;
  const int wr = w>>1, wc = w&1;
  f4v acc[4][4] = {};
  for(int k0 = 0; k0 < 768; k0 += 32){
    __syncthreads();
    for(int i=0;i<2;i++){
      int off = i*4096 + w*1024 + lane*16;
      int row = off>>6, kk = (off&63)>>1;
      glds16(A  + (size_t)(m0+row)*768 + k0 + kk, (u16*)Al + i*2048 + w*512);
      glds16(Bt + (size_t)(n0+row)*768 + k0 + kk, (u16*)Bl + i*2048 + w*512);
    }
    __syncthreads();
    bf8v a[4], b[4];
    for(int mt=0;mt<4;mt++) a[mt] = *(const bf8v*)&Al[(wr*64+mt*16+c16)*32 + h4*8];
    for(int nt=0;nt<4;nt++) b[nt] = *(const bf8v*)&Bl[(wc*64+nt*16+c16)*32 + h4*8];
    for(int mt=0;mt<4;mt++) for(int nt=0;nt<4;nt++) acc[mt][nt] = mfma32(a[mt], b[nt], acc[mt][nt]);
  }
  for(int nt=0;nt<4;nt++){
    int col = n0 + wc*64 + nt*16 + c16;
    float bv = bias[col];
    for(int mt=0;mt<4;mt++) for(int r=0;r<4;r++){
      int row = m0 + wr*64 + mt*16 + 4*h4 + r;
      out[(size_t)row*768 + col] = acc[mt][nt][r] + bv;
    }
  }
}

extern "C" void kernel_launch(void* const* d_in, const int* in_sizes, int n_in,
                              void* d_out, int out_size, void* d_ws, size_t ws_size,
                              hipStream_t stream){
  const float* x    = (const float*)d_in[0];
  const float* wqkv = (const float*)d_in[1];
  const float* bqkv = (const float*)d_in[2];
  const float* wo   = (const float*)d_in[3];
  const float* bo   = (const float*)d_in[4];
  const float* rph  = (const float*)d_in[5];
  const float* rpw  = (const float*)d_in[6];
  float* out = (float*)d_out;

  size_t off = 0;
  auto alloc = [&](size_t bytes){ void* p = (char*)d_ws + off; off += (bytes + 255) & ~(size_t)255; return p; };
  u16* x_bf   = (u16*)alloc((size_t)HW*C*2);
  u16* wqkv_t = (u16*)alloc((size_t)2304*768*2);
  u16* wo_t   = (u16*)alloc((size_t)768*768*2);
  u16* q_buf  = (u16*)alloc((size_t)NH*HW*D*2);
  u16* k_buf  = (u16*)alloc((size_t)NH*HW*D*2);
  u16* v_buf  = (u16*)alloc((size_t)NH*HW*D*2);
  u16* rh_buf = (u16*)alloc((size_t)NH*64*64*64*2);
  u16* rw_buf = (u16*)alloc((size_t)NH*64*64*64*2);
  u16* o_buf  = (u16*)alloc((size_t)HW*C*2);

  int n4 = HW*C/4;
  qa_convx<<<(n4+255)/256, 256, 0, stream>>>(x, x_bf, n4);
  qa_transp<<<dim3(2304/32, 768/32), 256, 0, stream>>>(wqkv, wqkv_t, 768, 2304);
  qa_transp<<<dim3(768/32, 768/32),  256, 0, stream>>>(wo,   wo_t,   768, 768);
  qa_gemm_qkv<<<dim3(2304/128, HW/128), 256, 0, stream>>>(x_bf, wqkv_t, bqkv, q_buf, k_buf, v_buf);
  qa_rel<<<dim3(64, NH), 256, 0, stream>>>(q_buf, rph, rpw, rh_buf, rw_buf);
  qa_attn<<<768, 128, 0, stream>>>(q_buf, k_buf, v_buf, rh_buf, rw_buf, o_buf);
  qa_gemm_out<<<dim3(768/128, HW/128), 256, 0, stream>>>(o_buf, wo_t, bo, out);
}

// Round 3
// 144.584 us; speedup vs baseline: 1.3925x; 1.1337x over previous
//
#include <hip/hip_runtime.h>

#define DEVI __device__ __forceinline__
typedef unsigned short u16;
typedef unsigned int u32;
typedef __attribute__((ext_vector_type(4))) float f4v;
typedef __attribute__((ext_vector_type(8))) short bf8v;   // 8 bf16 for MFMA A/B
typedef __attribute__((ext_vector_type(4))) u32  u32x4;
typedef __attribute__((ext_vector_type(2))) u32  u32x2;
typedef __attribute__((ext_vector_type(4))) u16  u16x4;

#define AS1 __attribute__((address_space(1)))
#define AS3 __attribute__((address_space(3)))

DEVI u16 f2bf(float x){ union{float f;u32 u;} c{x}; u32 r=(c.u+0x7FFFu+((c.u>>16)&1u))>>16; return (u16)r; }
DEVI float bf2f(u16 b){ union{u32 u;float f;} c{(u32)b<<16}; return c.f; }
DEVI f4v mfma32(bf8v a, bf8v b, f4v c){ return __builtin_amdgcn_mfma_f32_16x16x32_bf16(a,b,c,0,0,0); }
DEVI unsigned lds_off(const void* p){ return (unsigned)(unsigned long)(AS3 const void*)p; }
DEVI void glds16(const void* g, void* l){
  __builtin_amdgcn_global_load_lds((AS1 void*)g, (AS3 void*)l, 16, 0, 0);
}

static constexpr int NH = 12, HW = 4096, D = 64, C = 768;
static constexpr float LOG2E = 1.44269504f;

// ---------------- kernel 1: fp32 -> bf16 convert (x) ----------------
__global__ void qa_convx(const float* __restrict__ x, u16* __restrict__ xb, int n4){
  int i = blockIdx.x*256 + threadIdx.x;
  if(i >= n4) return;
  f4v v = ((const f4v*)x)[i];
  u16x4 o; for(int j=0;j<4;j++) o[j] = f2bf(v[j]);
  ((u16x4*)xb)[i] = o;
}

// -------------- kernel 2: fp32 [R][Cc] -> bf16 [Cc][R] transpose --------------
__global__ void qa_transp(const float* __restrict__ in, u16* __restrict__ out, int R, int Cc){
  __shared__ float tl[32][33];
  int t = threadIdx.x;
  int r0 = blockIdx.y*32, c0 = blockIdx.x*32;
  int tr = t>>3, tc = (t&7)*4;
  f4v v = *(const f4v*)&in[(r0+tr)*Cc + c0 + tc];
  for(int j=0;j<4;j++) tl[tr][tc+j] = v[j];
  __syncthreads();
  int oc = t>>3, orr = (t&7)*4;
  u16x4 o; for(int j=0;j<4;j++) o[j] = f2bf(tl[orr+j][oc]);
  *(u16x4*)&out[(c0+oc)*R + r0 + orr] = o;
}

// -------------- kernel 3: QKV GEMM  (4096 x 2304 x 768) --------------
// A = x_bf [4096][768], Bt = wqkv_t [2304][768]. K scaled by 0.125*log2e on store.
__global__ __launch_bounds__(256,2) void qa_gemm_qkv(
    const u16* __restrict__ A, const u16* __restrict__ Bt, const float* __restrict__ bias,
    u16* __restrict__ qb, u16* __restrict__ kb, u16* __restrict__ vb){
  __shared__ u16 Al[128*32], Bl[128*32];
  const int t = threadIdx.x, lane = t&63, w = t>>6, c16 = lane&15, h4 = lane>>4;
  const int m0 = blockIdx.y*128, n0 = blockIdx.x*128;
  const int wr = w>>1, wc = w&1;
  f4v acc[4][4] = {};
  for(int k0 = 0; k0 < 768; k0 += 32){
    __syncthreads();
    for(int i=0;i<2;i++){
      int off = i*4096 + w*1024 + lane*16;        // byte offset within 8KB tile
      int row = off>>6, kk = (off&63)>>1;
      glds16(A  + (size_t)(m0+row)*768 + k0 + kk, (u16*)Al + i*2048 + w*512);
      glds16(Bt + (size_t)(n0+row)*768 + k0 + kk, (u16*)Bl + i*2048 + w*512);
    }
    __syncthreads();
    bf8v a[4], b[4];
    for(int mt=0;mt<4;mt++) a[mt] = *(const bf8v*)&Al[(wr*64+mt*16+c16)*32 + h4*8];
    for(int nt=0;nt<4;nt++) b[nt] = *(const bf8v*)&Bl[(wc*64+nt*16+c16)*32 + h4*8];
    for(int mt=0;mt<4;mt++) for(int nt=0;nt<4;nt++) acc[mt][nt] = mfma32(a[mt], b[nt], acc[mt][nt]);
  }
  for(int nt=0;nt<4;nt++){
    int col = n0 + wc*64 + nt*16 + c16;
    float bv = bias[col];
    int which = col/768, head = (col>>6)%12, d = col&63;
    u16* dst = which==0 ? qb : (which==1 ? kb : vb);
    float sc = (which==1) ? 0.125f*LOG2E : 1.0f;
    for(int mt=0;mt<4;mt++) for(int r=0;r<4;r++){
      int row = m0 + wr*64 + mt*16 + 4*h4 + r;
      dst[((size_t)(head<<12)+row)*64 + d] = f2bf((acc[mt][nt][r] + bv)*sc);
    }
  }
}

// -------------- kernel 4: rel-pos bias tables via MFMA (scaled by log2e) --------------
// RH_t[head][qh][kh][qw] (transposed!), RW[head][qh][qw][kw]
__global__ __launch_bounds__(256) void qa_rel(
    const u16* __restrict__ qbuf, const float* __restrict__ rph, const float* __restrict__ rpw,
    u16* __restrict__ RHt, u16* __restrict__ RW){
  const int t = threadIdx.x, lane = t&63, w = t>>6, c16 = lane&15, h4 = lane>>4;
  const int qh = blockIdx.x, head = blockIdx.y;
  __shared__ u16 ql[64*72], hl[64*72], wl[128*72];
  { // stage q (bf16) and tables (fp32->bf16)
    int row = t>>2, d0 = (t&3)*16;
    const u16* src = qbuf + ((size_t)(head<<12)+(qh<<6)+row)*64 + d0;
    *(u32x4*)&ql[row*72+d0]   = *(const u32x4*)src;
    *(u32x4*)&ql[row*72+d0+8] = *(const u32x4*)(src+8);
    for(int j=0;j<16;j++) hl[row*72+d0+j] = f2bf(rph[(qh+row)*64 + d0 + j]);
    int rw_r = t>>1, rd0 = (t&1)*32;
    for(int j=0;j<32;j++) wl[rw_r*72+rd0+j] = (rw_r<127) ? f2bf(rpw[rw_r*64+rd0+j]) : (u16)0;
  }
  __syncthreads();
  if(w < 2){ // G'[qw][c] = q @ hl^T ; kh = 63 - c
    bf8v a[2][2]; f4v acc[2][4] = {};
    for(int mt=0;mt<2;mt++) for(int ch=0;ch<2;ch++)
      a[mt][ch] = *(const bf8v*)&ql[(w*32+mt*16+c16)*72 + ch*32 + h4*8];
    for(int nt=0;nt<4;nt++) for(int ch=0;ch<2;ch++){
      bf8v b = *(const bf8v*)&hl[(nt*16+c16)*72 + ch*32 + h4*8];
      for(int mt=0;mt<2;mt++) acc[mt][nt] = mfma32(a[mt][ch], b, acc[mt][nt]);
    }
    for(int mt=0;mt<2;mt++) for(int nt=0;nt<4;nt++) for(int r=0;r<4;r++){
      int qw = w*32+mt*16+4*h4+r, c = nt*16+c16, kh = 63 - c;
      RHt[((size_t)(head*64+qh)*64+kh)*64 + qw] = f2bf(acc[mt][nt][r]*LOG2E);
    }
  } else { // G[qw][c] = q @ wl^T (128 cols); kw = qw + 63 - c
    bf8v a[2][2]; f4v acc[2][8] = {};
    for(int mt=0;mt<2;mt++) for(int ch=0;ch<2;ch++)
      a[mt][ch] = *(const bf8v*)&ql[((w-2)*32+mt*16+c16)*72 + ch*32 + h4*8];
    for(int nt=0;nt<8;nt++) for(int ch=0;ch<2;ch++){
      bf8v b = *(const bf8v*)&wl[(nt*16+c16)*72 + ch*32 + h4*8];
      for(int mt=0;mt<2;mt++) acc[mt][nt] = mfma32(a[mt][ch], b, acc[mt][nt]);
    }
    for(int mt=0;mt<2;mt++) for(int nt=0;nt<8;nt++) for(int r=0;r<4;r++){
      int qw = (w-2)*32+mt*16+4*h4+r, c = nt*16+c16, kw = qw + 63 - c;
      if((unsigned)kw < 64u) RW[((size_t)(head*64+qh)*64+qw)*64 + kw] = f2bf(acc[mt][nt][r]*LOG2E);
    }
  }
}

// -------------- kernel 5: fused flash attention --------------
// block = 256 threads (4 waves x 16 qrows = 64 qrows), grid 768 (XCD-swizzled).
// Swapped QK^T (S^T in regs), in-register P^T frags, O^T output, glds16 dbuf pipeline.
__global__ __launch_bounds__(256,3) void qa_attn(
    const u16* __restrict__ qb, const u16* __restrict__ kb, const u16* __restrict__ vb,
    const u16* __restrict__ RHt, const u16* __restrict__ RW, u16* __restrict__ ob){
  __shared__ u16 Kl[2][4096];   // [buf][key][d], content at byte b = K[b ^ ((b>>7&7)<<4)]
  __shared__ u16 Vl[2][4096];   // [buf], subtiled: (d>>4)*2048B + key*32B + (d&15)*2B
  __shared__ u16 RHl[4096];     // [kt][qrow] for this (head, qt)
  const int t = threadIdx.x, lane = t&63, w = t>>6, c16 = lane&15, h4 = lane>>4;
  const int bid = blockIdx.x;
  const int wid = (bid&7)*96 + (bid>>3);       // XCD swizzle: <=2 heads per XCD
  const int head = wid>>6, qt = wid&63;

  // prologue: stage RH tile (linear 8KB)
  const u16* rhg = RHt + ((size_t)(head*64+qt))*4096;
  for(int i=0;i<2;i++)
    glds16(rhg + (i*256 + t)*8, (u16*)RHl + (i*256 + w*64)*8);

  // staging source offsets (16B units), fold K swizzle / V subtile permutation into source
  int koff[2], voff[2];
  for(int i=0;i<2;i++){
    int u = i*256 + t;
    koff[i] = (u ^ ((u>>3)&7))*8;                      // elements
    int key = ((u>>1)&3) | (((u>>3)&15)<<2);
    int d0  = ((u&1)<<3) | (((u>>7)&3)<<4);
    voff[i] = key*64 + d0;
  }
  const u16* kg = kb + (size_t)head*262144;
  const u16* vg = vb + (size_t)head*262144;
  const u16* kp = kg; const u16* vp = vg;
  for(int i=0;i<2;i++){                                 // tile 0 -> buf 0
    glds16(kp + koff[i], (u16*)Kl[0] + (i*256 + w*64)*8);
    glds16(vp + voff[i], (u16*)Vl[0] + (i*256 + w*64)*8);
  }
  kp += 4096; vp += 4096;

  // Q fragments (B-operand): lane holds Q[qrow = q0r+c16][d = 8*h4+j]
  const int q0r = qt*64 + w*16;
  bf8v qa[2];
  {
    const u16* qsrc = qb + ((size_t)head*4096 + q0r + c16)*64;
    qa[0] = *(const bf8v*)(qsrc + h4*8);
    qa[1] = *(const bf8v*)(qsrc + 32 + h4*8);
  }
  // RW bias in registers: rw[nt][r] for kw = nt*16+4*h4+r (already *log2e)
  float rw[4][4];
  for(int nt=0;nt<4;nt++) for(int r=0;r<4;r++){
    int qw = w*16 + c16, kw = nt*16 + 4*h4 + r;
    rw[nt][r] = bf2f(RW[(((size_t)(head*64+qt))*64 + qw)*64 + kw]);
  }

  f4v oacc[4] = {}; float ps = 0.f;
  unsigned vcur = lds_off(Vl) + lane*8;
  const int kq0 = (h4*16) ^ ((c16&7)<<4);
  const int kq1 = (h4*16 + 64) ^ ((c16&7)<<4);
  const int kA  = c16*128;

  for(int kt=0; kt<64; kt++){
    // issue next tile into the other buffer (kt=63 wraps harmlessly to tile 0)
    if(kt == 63){ kp = kg; vp = vg; }
    {
      u16* Kn = (u16*)Kl[(kt+1)&1]; u16* Vn = (u16*)Vl[(kt+1)&1];
      for(int i=0;i<2;i++){
        glds16(kp + koff[i], Kn + (i*256 + w*64)*8);
        glds16(vp + voff[i], Vn + (i*256 + w*64)*8);
      }
    }
    kp += 4096; vp += 4096;
    asm volatile("s_waitcnt vmcnt(4)\n\ts_barrier" ::: "memory");  // tile kt ready; kt+1 in flight

    const char* Kc = (const char*)Kl + (kt&1)*8192;
    float rh = bf2f(RHl[kt*64 + w*16 + c16]);
    f4v p[4];
    #pragma unroll
    for(int nt=0;nt<4;nt++){
      bf8v k0 = *(const bf8v*)(Kc + kA + nt*2048 + kq0);
      bf8v k1 = *(const bf8v*)(Kc + kA + nt*2048 + kq1);
      f4v s;
      for(int r=0;r<4;r++) s[r] = rh + rw[nt][r];
      s = mfma32(k0, qa[0], s);          // S^T[key=nt*16+4h4+r][qrow=c16]
      s = mfma32(k1, qa[1], s);
      f4v pe;
      for(int r=0;r<4;r++) pe[r] = __builtin_amdgcn_exp2f(s[r]);
      p[nt] = pe;
      ps += pe[0]+pe[1]+pe[2]+pe[3];
    }
    // pack P^T fragments: pb[half] elem e = p[half*2 + (e>>2)][e&3]
    union U8 { u32 w[4]; bf8v v; };
    U8 pb[2];
    #pragma unroll
    for(int half=0;half<2;half++)
      #pragma unroll
      for(int i=0;i<4;i++){
        int nt = half*2 + (i>>1), r0 = (i&1)*2;
        asm("v_cvt_pk_bf16_f32 %0, %1, %2"
            : "=v"(pb[half].w[i]) : "v"(p[nt][r0]), "v"(p[nt][r0+1]));
      }
    // PV: A = V^T frag via tr-reads (keys 4h4+(e&3)+16(e>>2) matches pb sigma)
    #pragma unroll
    for(int dt=0;dt<4;dt++){
      unsigned long t00,t01,t10,t11;
      asm volatile(
        "ds_read_b64_tr_b16 %0, %4 offset:%c5\n\t"
        "ds_read_b64_tr_b16 %1, %4 offset:%c6\n\t"
        "ds_read_b64_tr_b16 %2, %4 offset:%c7\n\t"
        "ds_read_b64_tr_b16 %3, %4 offset:%c8\n\t"
        "s_waitcnt lgkmcnt(0)"
        : "=&v"(t00), "=&v"(t01), "=&v"(t10), "=&v"(t11)
        : "v"(vcur), "i"(dt*2048), "i"(dt*2048+512), "i"(dt*2048+1024), "i"(dt*2048+1536)
        : "memory");
      union { struct{ unsigned long a,b; } q; bf8v v; } v01, v23;
      v01.q.a = t00; v01.q.b = t01; v23.q.a = t10; v23.q.b = t11;
      oacc[dt] = mfma32(v01.v, pb[0].v, oacc[dt]);
      oacc[dt] = mfma32(v23.v, pb[1].v, oacc[dt]);
    }
    asm volatile("s_waitcnt lgkmcnt(0)\n\ts_barrier" ::: "memory");  // reads done before overwrite
    vcur ^= 8192;
  }
  asm volatile("s_waitcnt vmcnt(0)" ::: "memory");  // drain wrap-around DMA before exit

  {
    float v = ps;
    v += __shfl_xor(v, 16); v += __shfl_xor(v, 32);
    float inv = 1.0f / v;
    const size_t orow = (size_t)(q0r + c16)*768 + head*64;
    #pragma unroll
    for(int dt=0;dt<4;dt++){
      u16x4 ov;
      for(int r=0;r<4;r++) ov[r] = f2bf(oacc[dt][r]*inv);
      *(u16x4*)&ob[orow + dt*16 + 4*h4] = ov;     // O^T rows d=dt*16+4h4+r, col qrow
    }
  }
}

// -------------- kernel 6: output GEMM (4096 x 768 x 768) --------------
__global__ __launch_bounds__(256,2) void qa_gemm_out(
    const u16* __restrict__ A, const u16* __restrict__ Bt, const float* __restrict__ bias,
    float* __restrict__ out){
  __shared__ u16 Al[128*32], Bl[128*32];
  const int t = threadIdx.x, lane = t&63, w = t>>6, c16 = lane&15, h4 = lane>>4;
  const int m0 = blockIdx.y*128, n0 = blockIdx.x*128;
  const int wr = w>>1, wc = w&1;
  f4v acc[4][4] = {};
  for(int k0 = 0; k0 < 768; k0 += 32){
    __syncthreads();
    for(int i=0;i<2;i++){
      int off = i*4096 + w*1024 + lane*16;
      int row = off>>6, kk = (off&63)>>1;
      glds16(A  + (size_t)(m0+row)*768 + k0 + kk, (u16*)Al + i*2048 + w*512);
      glds16(Bt + (size_t)(n0+row)*768 + k0 + kk, (u16*)Bl + i*2048 + w*512);
    }
    __syncthreads();
    bf8v a[4], b[4];
    for(int mt=0;mt<4;mt++) a[mt] = *(const bf8v*)&Al[(wr*64+mt*16+c16)*32 + h4*8];
    for(int nt=0;nt<4;nt++) b[nt] = *(const bf8v*)&Bl[(wc*64+nt*16+c16)*32 + h4*8];
    for(int mt=0;mt<4;mt++) for(int nt=0;nt<4;nt++) acc[mt][nt] = mfma32(a[mt], b[nt], acc[mt][nt]);
  }
  for(int nt=0;nt<4;nt++){
    int col = n0 + wc*64 + nt*16 + c16;
    float bv = bias[col];
    for(int mt=0;mt<4;mt++) for(int r=0;r<4;r++){
      int row = m0 + wr*64 + mt*16 + 4*h4 + r;
      out[(size_t)row*768 + col] = acc[mt][nt][r] + bv;
    }
  }
}

extern "C" void kernel_launch(void* const* d_in, const int* in_sizes, int n_in,
                              void* d_out, int out_size, void* d_ws, size_t ws_size,
                              hipStream_t stream){
  const float* x    = (const float*)d_in[0];
  const float* wqkv = (const float*)d_in[1];
  const float* bqkv = (const float*)d_in[2];
  const float* wo   = (const float*)d_in[3];
  const float* bo   = (const float*)d_in[4];
  const float* rph  = (const float*)d_in[5];
  const float* rpw  = (const float*)d_in[6];
  float* out = (float*)d_out;

  size_t off = 0;
  auto alloc = [&](size_t bytes){ void* p = (char*)d_ws + off; off += (bytes + 255) & ~(size_t)255; return p; };
  u16* x_bf   = (u16*)alloc((size_t)HW*C*2);
  u16* wqkv_t = (u16*)alloc((size_t)2304*768*2);
  u16* wo_t   = (u16*)alloc((size_t)768*768*2);
  u16* q_buf  = (u16*)alloc((size_t)NH*HW*D*2);
  u16* k_buf  = (u16*)alloc((size_t)NH*HW*D*2);
  u16* v_buf  = (u16*)alloc((size_t)NH*HW*D*2);
  u16* rh_buf = (u16*)alloc((size_t)NH*64*64*64*2);
  u16* rw_buf = (u16*)alloc((size_t)NH*64*64*64*2);
  u16* o_buf  = (u16*)alloc((size_t)HW*C*2);

  int n4 = HW*C/4;
  qa_convx<<<(n4+255)/256, 256, 0, stream>>>(x, x_bf, n4);
  qa_transp<<<dim3(2304/32, 768/32), 256, 0, stream>>>(wqkv, wqkv_t, 768, 2304);
  qa_transp<<<dim3(768/32, 768/32),  256, 0, stream>>>(wo,   wo_t,   768, 768);
  qa_gemm_qkv<<<dim3(2304/128, HW/128), 256, 0, stream>>>(x_bf, wqkv_t, bqkv, q_buf, k_buf, v_buf);
  qa_rel<<<dim3(64, NH), 256, 0, stream>>>(q_buf, rph, rpw, rh_buf, rw_buf);
  qa_attn<<<768, 256, 0, stream>>>(q_buf, k_buf, v_buf, rh_buf, rw_buf, o_buf);
  qa_gemm_out<<<dim3(768/128, HW/128), 256, 0, stream>>>(o_buf, wo_t, bo, out);
}